// Round 11
// baseline (179.977 us; speedup 1.0000x reference)
//
#include <hip/hip_runtime.h>
#include <hip/hip_bf16.h>
#include <math.h>

#define B_   16
#define L_   1024
#define F_   64
#define D_   256
#define S_   2
#define N_   16
#define H_   32
#define EPS_ 1e-5f
#define BL_  (B_*L_)
#define NCH_ 16         // t-chunks for the parallel scan
#define TC_  (L_/NCH_)  // 64 timesteps per chunk (one sub-chunk)
#define TSTR_ 68        // scan tile stride (floats); 272B rows, 16B aligned
#define LOG2E_ 1.44269504088896340736f
#define XBLK_ (BL_*F_/1024)   // 1024 xsplit blocks

typedef __attribute__((ext_vector_type(8))) short  bf16x8;
typedef __attribute__((ext_vector_type(4))) float  f32x4;
typedef __attribute__((ext_vector_type(2))) float  f32x2;

typedef const __attribute__((address_space(1))) void* gas_ptr;
typedef __attribute__((address_space(3))) void*       las_ptr;

#if defined(__has_builtin)
# if __has_builtin(__builtin_amdgcn_exp2f)
#  define EXP2(x) __builtin_amdgcn_exp2f(x)
#  define ASCALE_ LOG2E_
# endif
#endif
#ifndef EXP2
# define EXP2(x) __expf(x)
# define ASCALE_ 1.0f
#endif

__device__ inline void async_copy16(const void* g, void* l) {
    __builtin_amdgcn_global_load_lds((gas_ptr)g, (las_ptr)l, 16, 0, 0);
}

__device__ inline unsigned short f2bf_rne(float x) {
    union { float f; unsigned u; } v; v.f = x;
    unsigned r = v.u + 0x7fff + ((v.u >> 16) & 1);
    return (unsigned short)(r >> 16);
}

// ---------------------------------------------------------------------------
// Kernel 1: combined prep (x -> bf16, composed weights -> bf16).
//  blocks [0, XBLK_):      x_hi = bf16(x)
//  blocks [XBLK_, +256):   Weff cols (4 jobs x 64 thr) + biases
//  blocks [+256, +64):     WinT rows (4 jobs)
//  blocks [+320, +8):      WBe cols (4 jobs) + bbias
// ---------------------------------------------------------------------------
__global__ __launch_bounds__(256) void k_prep(const float* __restrict__ x,
                                              const float* __restrict__ Win,
                                              const float* __restrict__ bin,
                                              const float* __restrict__ Wd,
                                              const float* __restrict__ bd,
                                              const float* __restrict__ Wt,
                                              const float* __restrict__ WB,
                                              unsigned short* __restrict__ x_hi,
                                              unsigned short* __restrict__ Weff_hi,
                                              float* __restrict__ bias_eff,
                                              unsigned short* __restrict__ WinT_hi,
                                              unsigned short* __restrict__ WBe_hi,
                                              float* __restrict__ bbias)
{
    const int blk = blockIdx.x;
    const int tid = threadIdx.x;

    if (blk < XBLK_) {
        const int i = (blk * 256 + tid) * 4;
        float4 v = *(const float4*)(x + i);
        ushort4 h4;
        h4.x = f2bf_rne(v.x);
        h4.y = f2bf_rne(v.y);
        h4.z = f2bf_rne(v.z);
        h4.w = f2bf_rne(v.w);
        *(ushort4*)(x_hi + i) = h4;
        return;
    }

    const int job4 = blk - XBLK_;
    const int j    = tid >> 6;          // sub-job 0..3
    const int f    = tid & 63;
    const int job  = job4 * 4 + j;

    __shared__ float col[4][D_];

    if (job < 1024) {                   // Weff: s = job>>9, n = job&511
        const int s = job >> 9, n = job & 511;
        const float* W = (n < 256) ? (Wd + (size_t)s * D_ * D_) : (Wt + (size_t)s * D_ * D_);
        const int e = n & 255;
        for (int d = f; d < D_; d += 64) col[j][d] = W[(size_t)d * D_ + e];
        __syncthreads();
        float a = 0.f;
        for (int d = 0; d < D_; ++d) a += Win[(size_t)f * D_ + d] * col[j][d];
        Weff_hi[((size_t)s * 512 + n) * F_ + f] = f2bf_rne(a);
        if (f == 0) {
            float bb = 0.f;
            for (int d = 0; d < D_; ++d) bb += bin[d] * col[j][d];
            if (n < 256) bb += bd[s * D_ + e];
            bias_eff[s * 512 + n] = bb;
        }
    } else if (job < 1024 + D_) {       // WinT
        const int d = job - 1024;
        WinT_hi[(size_t)d * F_ + f] = f2bf_rne(Win[(size_t)f * D_ + d]);
    } else {                            // WBe
        const int idx = job - (1024 + D_);
        const int s = idx >> 4, n = idx & 15;
        const float* wb = WB + (size_t)s * D_ * N_;
        float a = 0.f;
        for (int d = 0; d < D_; ++d) a += Win[(size_t)f * D_ + d] * wb[(size_t)d * N_ + n];
        WBe_hi[((size_t)s * N_ + n) * F_ + f] = f2bf_rne(a);
        if (f == 0) {
            float bb = 0.f;
            for (int d = 0; d < D_; ++d) bb += bin[d] * wb[(size_t)d * N_ + n];
            bbias[s * N_ + n] = bb;
        }
    }
}

// ---------------------------------------------------------------------------
// Kernel 2: FUSED gemm + activation + scan, bf16 GEMM, single 64-t chunk
// per block (NCH=16) -> exactly 2 barriers, no sub-chunk loop.
// ---------------------------------------------------------------------------
__global__ __launch_bounds__(256) void k_fused_scan(
        const unsigned short* __restrict__ x_hi,
        const unsigned short* __restrict__ Weff_hi,
        const unsigned short* __restrict__ WinT_hi,
        const unsigned short* __restrict__ WBe_hi,
        const float* __restrict__ bias_eff,
        const float* __restrict__ bin,
        const float* __restrict__ bbias,
        const float* __restrict__ A_log,
        float* __restrict__ part,
        float* __restrict__ csum)
{
    const int dtile = blockIdx.x >> 4;
    const int c     = blockIdx.x & 15;
    const int b     = blockIdx.y;
    const int s     = blockIdx.z;
    const int d0    = dtile * 16;
    const int tid   = threadIdx.x;
    const int wid   = tid >> 6;
    const int lane  = tid & 63;
    const int l15   = lane & 15;
    const int quad  = lane >> 4;
    const int dl    = tid & 15;
    const int nl    = tid >> 4;

    __shared__ unsigned short Wh[64 * F_];  // [col][f]: 0-15 d,16-31 tau,32-47 Win,48-63 WB
    __shared__ float sdl[16][TSTR_];        // [d][t] delta
    __shared__ float sq [16][TSTR_];        // [d][t] delta*h
    __shared__ float sb [16][TSTR_];        // [n][t] Bm

    const int r8 = lane >> 3;
    const int c8 = lane & 7;

    // ---- stage W strip (wave wid = col group wid)
    #pragma unroll
    for (int call = 0; call < 2; ++call) {
        const int rr = call * 8 + r8;
        const int ar = wid * 16 + rr;
        const int lc = (c8 - ar) & 7;
        const unsigned short* gh;
        if (wid == 0)      gh = Weff_hi + ((size_t)s * 512 + d0 + rr) * F_ + lc * 8;
        else if (wid == 1) gh = Weff_hi + ((size_t)s * 512 + 256 + d0 + rr) * F_ + lc * 8;
        else if (wid == 2) gh = WinT_hi + ((size_t)(d0 + rr)) * F_ + lc * 8;
        else               gh = WBe_hi + ((size_t)s * N_ + rr) * F_ + lc * 8;
        async_copy16(gh, &Wh[(wid * 16 + call * 8) * F_]);
    }

    const float bias_d = bias_eff[s * 512 + d0 + l15];
    const float bias_t = bias_eff[s * 512 + 256 + d0 + l15];
    const float bin_v  = bin[d0 + l15];
    const float bb_v   = bbias[s * N_ + l15];
    const float A2 = -__expf(A_log[((size_t)s * D_ + d0 + dl) * N_ + nl]) * ASCALE_;

    // A-fragments for this block's 64-t chunk
    const int qoff = quad * 8;
    bf16x8 fah0, fah1;
    {
        const size_t rowb = ((size_t)b * L_ + c * TC_ + wid * 16 + l15) * F_;
        fah0 = *(const bf16x8*)(x_hi + rowb + qoff);
        fah1 = *(const bf16x8*)(x_hi + rowb + 32 + qoff);
    }
    __syncthreads();   // W staged

    // ---- MFMA: this wave's 16 t-rows x 4 col groups, K=64
    f32x4 acc[4];
    #pragma unroll
    for (int g = 0; g < 4; ++g) acc[g] = (f32x4){0.f, 0.f, 0.f, 0.f};
    #pragma unroll
    for (int ks = 0; ks < 2; ++ks) {
        bf16x8 ah = ks ? fah1 : fah0;
        #pragma unroll
        for (int g = 0; g < 4; ++g) {
            const int brow = g * 16 + l15;
            const int pcB  = ((ks * 4 + quad) + brow) & 7;
            bf16x8 bh = *(const bf16x8*)&Wh[brow * F_ + pcB * 8];
            acc[g] = __builtin_amdgcn_mfma_f32_16x16x32_bf16(ah, bh, acc[g], 0, 0, 0);
        }
    }

    // ---- epilogue: C layout col=l15, row=quad*4+r -> transposed tiles
    {
        f32x4 wd_, wq_, wb_;
        #pragma unroll
        for (int r = 0; r < 4; ++r) {
            const float pd  = acc[0][r] + bias_d;
            const float sp  = fmaxf(pd, 0.f) + __logf(1.f + __expf(-fabsf(pd)));
            const float sg  = 1.f / (1.f + __expf(-(acc[1][r] + bias_t)));
            const float dlt = sp * sg;
            const float hv  = acc[2][r] + bin_v;
            wd_[r] = dlt;
            wq_[r] = dlt * hv;
            wb_[r] = acc[3][r] + bb_v;
        }
        const int tcol = wid * 16 + quad * 4;
        *(f32x4*)&sdl[l15][tcol] = wd_;
        *(f32x4*)&sq [l15][tcol] = wq_;
        *(f32x4*)&sb [l15][tcol] = wb_;
    }
    __syncthreads();

    // ---- backward suffix scan over the 64-t chunk, 4 t per iteration
    f32x2 st01 = {0.f, 0.f};
    f32x2 st23 = {0.f, 0.f};
    float As = 0.f;
    #pragma unroll 4
    for (int tt = TC_ - 4; tt >= 0; tt -= 4) {
        f32x4 dp = *(const f32x4*)&sdl[dl][tt];
        f32x4 qp = *(const f32x4*)&sq [dl][tt];
        f32x4 bp = *(const f32x4*)&sb [nl][tt];
        const float a2v = fmaf(A2, dp.w, As);
        const float a1v = fmaf(A2, dp.z, a2v);
        const float a0v = fmaf(A2, dp.y, a1v);
        f32x2 e01, e23;
        e23.y = EXP2(As);
        e23.x = EXP2(a2v);
        e01.y = EXP2(a1v);
        e01.x = EXP2(a0v);
        f32x2 q01 = {qp.x, qp.y}, q23 = {qp.z, qp.w};
        f32x2 b01 = {bp.x, bp.y}, b23 = {bp.z, bp.w};
        st01 = q01 * b01 * e01 + st01;
        st23 = q23 * b23 * e23 + st23;
        As = fmaf(A2, dp.x, a0v);
    }

    const size_t pb = ((size_t)s * B_ + b) * NCH_ + c;
    part[(pb * D_ + d0 + dl) * N_ + nl] = (st01.x + st01.y) + (st23.x + st23.y);
    if (nl == 0)
        csum[pb * D_ + d0 + dl] = As / A2;
}

// ---------------------------------------------------------------------------
// Kernel 3: fused tail — chunk-combine + C-readout + Wout matvec + LN + MLP.
// One block per batch element b; ys kept in LDS (no global round-trip).
// ---------------------------------------------------------------------------
__global__ __launch_bounds__(256) void k_tail(const float* __restrict__ x,
                                              const float* __restrict__ Win,
                                              const float* __restrict__ bin,
                                              const float* __restrict__ part,
                                              const float* __restrict__ csum,
                                              const float* __restrict__ A_log,
                                              const float* __restrict__ WC,
                                              const float* __restrict__ Dp,
                                              const float* __restrict__ Wout,
                                              const float* __restrict__ ln_g,
                                              const float* __restrict__ ln_b,
                                              const float* __restrict__ W1,
                                              const float* __restrict__ b1,
                                              const float* __restrict__ W2,
                                              const float* __restrict__ b2,
                                              float* __restrict__ out)
{
    const int b   = blockIdx.x;
    const int tid = threadIdx.x;

    __shared__ float xr[F_];
    __shared__ float hl[D_];
    __shared__ float cm[S_][N_];
    __shared__ float cred[N_][17];
    __shared__ float ysl[S_][D_];
    __shared__ float zv[D_];
    __shared__ float red1[256];
    __shared__ float red2[256];
    __shared__ float r1[H_];

    if (tid < F_) xr[tid] = x[((size_t)b * L_ + (L_ - 1)) * F_ + tid];
    __syncthreads();

    {   // h_last[d] = x_last . Win[:,d] + bin[d]
        float a = bin[tid];
        for (int f = 0; f < F_; ++f) a += xr[f] * Win[(size_t)f * D_ + tid];
        hl[tid] = a;
    }
    __syncthreads();

    // cm[s][n] = sum_d hl[d] * WC[s][d][n]
    for (int s = 0; s < S_; ++s) {
        const int n  = tid & 15;
        const int dq = tid >> 4;
        float a = 0.f;
        for (int d = dq * 16; d < dq * 16 + 16; ++d)
            a += hl[d] * WC[((size_t)s * D_ + d) * N_ + n];
        cred[n][dq] = a;
        __syncthreads();
        if (tid < N_) {
            float acc = 0.f;
            #pragma unroll
            for (int q = 0; q < 16; ++q) acc += cred[tid][q];
            cm[s][tid] = acc;
        }
        __syncthreads();
    }

    // ys[s][d]: inline chunk-combine (thread = d)
    for (int s = 0; s < S_; ++s) {
        const float* al = A_log + ((size_t)s * D_ + tid) * N_;
        float a2v[N_];
        #pragma unroll
        for (int n = 0; n < N_; ++n) a2v[n] = -__expf(al[n]);
        const size_t cbase = ((size_t)s * B_ + b) * NCH_;
        float acc = 0.f;
        float tail = 0.f;
        for (int c = NCH_ - 1; c >= 0; --c) {
            const float* pp = part + ((cbase + c) * D_ + tid) * N_;
            #pragma unroll
            for (int n = 0; n < N_; ++n)
                acc += cm[s][n] * __expf(a2v[n] * tail) * pp[n];
            tail += csum[(cbase + c) * D_ + tid];
        }
        ysl[s][tid] = acc + hl[tid] * Dp[s * D_ + tid];
    }
    __syncthreads();

    // last[e] = (1/S) sum_{s,d} ys[s][d] * Wout[s][d][e]   (e = tid, coalesced)
    float v;
    {
        float a = 0.f;
        #pragma unroll 2
        for (int s = 0; s < S_; ++s) {
            const float* wo = Wout + (size_t)s * D_ * D_;
            for (int d = 0; d < D_; ++d) a += ysl[s][d] * wo[(size_t)d * D_ + tid];
        }
        v = a * (1.f / S_);
    }

    red1[tid] = v;
    red2[tid] = v * v;
    __syncthreads();
    for (int off = 128; off > 0; off >>= 1) {
        if (tid < off) { red1[tid] += red1[tid + off]; red2[tid] += red2[tid + off]; }
        __syncthreads();
    }
    const float mu  = red1[0] * (1.f / D_);
    const float var = red2[0] * (1.f / D_) - mu * mu;
    const float z = (v - mu) * rsqrtf(var + EPS_) * ln_g[tid] + ln_b[tid];
    zv[tid] = z;
    __syncthreads();

    if (tid < H_) {
        float a = b1[tid];
        for (int e = 0; e < D_; ++e) a += zv[e] * W1[(size_t)e * H_ + tid];
        r1[tid] = fmaxf(a, 0.f);
    }
    __syncthreads();
    if (tid == 0) {
        float a = b2[0];
        for (int j = 0; j < H_; ++j) a += r1[j] * W2[j];
        out[b] = a;
    }
}

// ---------------------------------------------------------------------------
extern "C" void kernel_launch(void* const* d_in, const int* in_sizes, int n_in,
                              void* d_out, int out_size, void* d_ws, size_t ws_size,
                              hipStream_t stream)
{
    const float* x     = (const float*)d_in[0];
    const float* Win   = (const float*)d_in[1];
    const float* bin   = (const float*)d_in[2];
    const float* Wd    = (const float*)d_in[3];
    const float* bd    = (const float*)d_in[4];
    const float* WB    = (const float*)d_in[5];
    const float* WC    = (const float*)d_in[6];
    const float* Wtau  = (const float*)d_in[7];
    const float* A_log = (const float*)d_in[8];
    const float* Dp    = (const float*)d_in[9];
    const float* Wout  = (const float*)d_in[10];
    const float* ln_g  = (const float*)d_in[11];
    const float* ln_b  = (const float*)d_in[12];
    const float* W1    = (const float*)d_in[13];
    const float* b1    = (const float*)d_in[14];
    const float* W2    = (const float*)d_in[15];
    const float* b2    = (const float*)d_in[16];
    float* out = (float*)d_out;

    char* ws = (char*)d_ws;
    const size_t MB = 1024 * 1024;
    const size_t KB = 1024;
    unsigned short* x_hi     = (unsigned short*)(ws);                      // 2 MiB
    unsigned short* Weff_hi  = (unsigned short*)(ws + 2 * MB);             // 128 KiB
    unsigned short* WinT_hi  = (unsigned short*)(ws + 2 * MB + 128 * KB);  // 32 KiB
    unsigned short* WBe_hi   = (unsigned short*)(ws + 2 * MB + 160 * KB);  // 4 KiB
    float*          bias_eff = (float*)(ws + 2 * MB + 164 * KB);           // 4 KiB
    float*          bbias    = (float*)(ws + 2 * MB + 168 * KB);           // 128 B
    float*          part     = (float*)(ws + 3 * MB);                      // 8 MiB (S,B,NCH,D,N)
    float*          csum     = (float*)(ws + 11 * MB);                     // 512 KiB

    hipLaunchKernelGGL(k_prep, dim3(XBLK_ + 328), dim3(256), 0, stream,
                       x, Win, bin, Wd, bd, Wtau, WB,
                       x_hi, Weff_hi, bias_eff, WinT_hi, WBe_hi, bbias);
    hipLaunchKernelGGL(k_fused_scan, dim3((D_ / 16) * NCH_, B_, S_), dim3(256), 0, stream,
                       x_hi, Weff_hi, WinT_hi, WBe_hi,
                       bias_eff, bin, bbias, A_log, part, csum);
    hipLaunchKernelGGL(k_tail, dim3(B_), dim3(256), 0, stream,
                       x, Win, bin, part, csum, A_log, WC, Dp, Wout,
                       ln_g, ln_b, W1, b1, W2, b2, out);
}

// Round 12
// 161.625 us; speedup vs baseline: 1.1135x; 1.1135x over previous
//
#include <hip/hip_runtime.h>
#include <hip/hip_bf16.h>
#include <math.h>

#define B_   16
#define L_   1024
#define F_   64
#define D_   256
#define S_   2
#define N_   16
#define H_   32
#define EPS_ 1e-5f
#define BL_  (B_*L_)
#define NCH_ 16         // t-chunks for the parallel scan
#define TC_  (L_/NCH_)  // 64 timesteps per chunk (one sub-chunk)
#define TSTR_ 68        // scan tile stride (floats); 272B rows, 16B aligned
#define LOG2E_ 1.44269504088896340736f
#define XBLK_ (BL_*F_/1024)   // 1024 xsplit blocks

typedef __attribute__((ext_vector_type(8))) short  bf16x8;
typedef __attribute__((ext_vector_type(4))) float  f32x4;
typedef __attribute__((ext_vector_type(2))) float  f32x2;

typedef const __attribute__((address_space(1))) void* gas_ptr;
typedef __attribute__((address_space(3))) void*       las_ptr;

#if defined(__has_builtin)
# if __has_builtin(__builtin_amdgcn_exp2f)
#  define EXP2(x) __builtin_amdgcn_exp2f(x)
#  define ASCALE_ LOG2E_
# endif
#endif
#ifndef EXP2
# define EXP2(x) __expf(x)
# define ASCALE_ 1.0f
#endif

__device__ inline void async_copy16(const void* g, void* l) {
    __builtin_amdgcn_global_load_lds((gas_ptr)g, (las_ptr)l, 16, 0, 0);
}

__device__ inline unsigned short f2bf_rne(float x) {
    union { float f; unsigned u; } v; v.f = x;
    unsigned r = v.u + 0x7fff + ((v.u >> 16) & 1);
    return (unsigned short)(r >> 16);
}

// ---------------------------------------------------------------------------
// Kernel 1: combined prep (x -> bf16, composed weights -> bf16).
// ---------------------------------------------------------------------------
__global__ __launch_bounds__(256) void k_prep(const float* __restrict__ x,
                                              const float* __restrict__ Win,
                                              const float* __restrict__ bin,
                                              const float* __restrict__ Wd,
                                              const float* __restrict__ bd,
                                              const float* __restrict__ Wt,
                                              const float* __restrict__ WB,
                                              unsigned short* __restrict__ x_hi,
                                              unsigned short* __restrict__ Weff_hi,
                                              float* __restrict__ bias_eff,
                                              unsigned short* __restrict__ WinT_hi,
                                              unsigned short* __restrict__ WBe_hi,
                                              float* __restrict__ bbias)
{
    const int blk = blockIdx.x;
    const int tid = threadIdx.x;

    if (blk < XBLK_) {
        const int i = (blk * 256 + tid) * 4;
        float4 v = *(const float4*)(x + i);
        ushort4 h4;
        h4.x = f2bf_rne(v.x);
        h4.y = f2bf_rne(v.y);
        h4.z = f2bf_rne(v.z);
        h4.w = f2bf_rne(v.w);
        *(ushort4*)(x_hi + i) = h4;
        return;
    }

    const int job4 = blk - XBLK_;
    const int j    = tid >> 6;          // sub-job 0..3
    const int f    = tid & 63;
    const int job  = job4 * 4 + j;

    __shared__ float col[4][D_];

    if (job < 1024) {                   // Weff: s = job>>9, n = job&511
        const int s = job >> 9, n = job & 511;
        const float* W = (n < 256) ? (Wd + (size_t)s * D_ * D_) : (Wt + (size_t)s * D_ * D_);
        const int e = n & 255;
        for (int d = f; d < D_; d += 64) col[j][d] = W[(size_t)d * D_ + e];
        __syncthreads();
        float a = 0.f;
        for (int d = 0; d < D_; ++d) a += Win[(size_t)f * D_ + d] * col[j][d];
        Weff_hi[((size_t)s * 512 + n) * F_ + f] = f2bf_rne(a);
        if (f == 0) {
            float bb = 0.f;
            for (int d = 0; d < D_; ++d) bb += bin[d] * col[j][d];
            if (n < 256) bb += bd[s * D_ + e];
            bias_eff[s * 512 + n] = bb;
        }
    } else if (job < 1024 + D_) {       // WinT
        const int d = job - 1024;
        WinT_hi[(size_t)d * F_ + f] = f2bf_rne(Win[(size_t)f * D_ + d]);
    } else {                            // WBe
        const int idx = job - (1024 + D_);
        const int s = idx >> 4, n = idx & 15;
        const float* wb = WB + (size_t)s * D_ * N_;
        float a = 0.f;
        for (int d = 0; d < D_; ++d) a += Win[(size_t)f * D_ + d] * wb[(size_t)d * N_ + n];
        WBe_hi[((size_t)s * N_ + n) * F_ + f] = f2bf_rne(a);
        if (f == 0) {
            float bb = 0.f;
            for (int d = 0; d < D_; ++d) bb += bin[d] * wb[(size_t)d * N_ + n];
            bbias[s * N_ + n] = bb;
        }
    }
}

// ---------------------------------------------------------------------------
// Kernel 2: FUSED gemm + activation + scan, bf16 GEMM, single 64-t chunk
// per block (NCH=16) -> exactly 2 barriers, no sub-chunk loop.
// ---------------------------------------------------------------------------
__global__ __launch_bounds__(256) void k_fused_scan(
        const unsigned short* __restrict__ x_hi,
        const unsigned short* __restrict__ Weff_hi,
        const unsigned short* __restrict__ WinT_hi,
        const unsigned short* __restrict__ WBe_hi,
        const float* __restrict__ bias_eff,
        const float* __restrict__ bin,
        const float* __restrict__ bbias,
        const float* __restrict__ A_log,
        float* __restrict__ part,
        float* __restrict__ csum)
{
    const int dtile = blockIdx.x >> 4;
    const int c     = blockIdx.x & 15;
    const int b     = blockIdx.y;
    const int s     = blockIdx.z;
    const int d0    = dtile * 16;
    const int tid   = threadIdx.x;
    const int wid   = tid >> 6;
    const int lane  = tid & 63;
    const int l15   = lane & 15;
    const int quad  = lane >> 4;
    const int dl    = tid & 15;
    const int nl    = tid >> 4;

    __shared__ unsigned short Wh[64 * F_];  // [col][f]: 0-15 d,16-31 tau,32-47 Win,48-63 WB
    __shared__ float sdl[16][TSTR_];        // [d][t] delta
    __shared__ float sq [16][TSTR_];        // [d][t] delta*h
    __shared__ float sb [16][TSTR_];        // [n][t] Bm

    const int r8 = lane >> 3;
    const int c8 = lane & 7;

    // ---- stage W strip (wave wid = col group wid)
    #pragma unroll
    for (int call = 0; call < 2; ++call) {
        const int rr = call * 8 + r8;
        const int ar = wid * 16 + rr;
        const int lc = (c8 - ar) & 7;
        const unsigned short* gh;
        if (wid == 0)      gh = Weff_hi + ((size_t)s * 512 + d0 + rr) * F_ + lc * 8;
        else if (wid == 1) gh = Weff_hi + ((size_t)s * 512 + 256 + d0 + rr) * F_ + lc * 8;
        else if (wid == 2) gh = WinT_hi + ((size_t)(d0 + rr)) * F_ + lc * 8;
        else               gh = WBe_hi + ((size_t)s * N_ + rr) * F_ + lc * 8;
        async_copy16(gh, &Wh[(wid * 16 + call * 8) * F_]);
    }

    const float bias_d = bias_eff[s * 512 + d0 + l15];
    const float bias_t = bias_eff[s * 512 + 256 + d0 + l15];
    const float bin_v  = bin[d0 + l15];
    const float bb_v   = bbias[s * N_ + l15];
    const float A2 = -__expf(A_log[((size_t)s * D_ + d0 + dl) * N_ + nl]) * ASCALE_;

    // A-fragments for this block's 64-t chunk
    const int qoff = quad * 8;
    bf16x8 fah0, fah1;
    {
        const size_t rowb = ((size_t)b * L_ + c * TC_ + wid * 16 + l15) * F_;
        fah0 = *(const bf16x8*)(x_hi + rowb + qoff);
        fah1 = *(const bf16x8*)(x_hi + rowb + 32 + qoff);
    }
    __syncthreads();   // W staged

    // ---- MFMA: this wave's 16 t-rows x 4 col groups, K=64
    f32x4 acc[4];
    #pragma unroll
    for (int g = 0; g < 4; ++g) acc[g] = (f32x4){0.f, 0.f, 0.f, 0.f};
    #pragma unroll
    for (int ks = 0; ks < 2; ++ks) {
        bf16x8 ah = ks ? fah1 : fah0;
        #pragma unroll
        for (int g = 0; g < 4; ++g) {
            const int brow = g * 16 + l15;
            const int pcB  = ((ks * 4 + quad) + brow) & 7;
            bf16x8 bh = *(const bf16x8*)&Wh[brow * F_ + pcB * 8];
            acc[g] = __builtin_amdgcn_mfma_f32_16x16x32_bf16(ah, bh, acc[g], 0, 0, 0);
        }
    }

    // ---- epilogue: C layout col=l15, row=quad*4+r -> transposed tiles
    {
        f32x4 wd_, wq_, wb_;
        #pragma unroll
        for (int r = 0; r < 4; ++r) {
            const float pd  = acc[0][r] + bias_d;
            const float sp  = fmaxf(pd, 0.f) + __logf(1.f + __expf(-fabsf(pd)));
            const float sg  = 1.f / (1.f + __expf(-(acc[1][r] + bias_t)));
            const float dlt = sp * sg;
            const float hv  = acc[2][r] + bin_v;
            wd_[r] = dlt;
            wq_[r] = dlt * hv;
            wb_[r] = acc[3][r] + bb_v;
        }
        const int tcol = wid * 16 + quad * 4;
        *(f32x4*)&sdl[l15][tcol] = wd_;
        *(f32x4*)&sq [l15][tcol] = wq_;
        *(f32x4*)&sb [l15][tcol] = wb_;
    }
    __syncthreads();

    // ---- backward suffix scan over the 64-t chunk, 4 t per iteration
    f32x2 st01 = {0.f, 0.f};
    f32x2 st23 = {0.f, 0.f};
    float As = 0.f;
    #pragma unroll 4
    for (int tt = TC_ - 4; tt >= 0; tt -= 4) {
        f32x4 dp = *(const f32x4*)&sdl[dl][tt];
        f32x4 qp = *(const f32x4*)&sq [dl][tt];
        f32x4 bp = *(const f32x4*)&sb [nl][tt];
        const float a2v = fmaf(A2, dp.w, As);
        const float a1v = fmaf(A2, dp.z, a2v);
        const float a0v = fmaf(A2, dp.y, a1v);
        f32x2 e01, e23;
        e23.y = EXP2(As);
        e23.x = EXP2(a2v);
        e01.y = EXP2(a1v);
        e01.x = EXP2(a0v);
        f32x2 q01 = {qp.x, qp.y}, q23 = {qp.z, qp.w};
        f32x2 b01 = {bp.x, bp.y}, b23 = {bp.z, bp.w};
        st01 = q01 * b01 * e01 + st01;
        st23 = q23 * b23 * e23 + st23;
        As = fmaf(A2, dp.x, a0v);
    }

    const size_t pb = ((size_t)s * B_ + b) * NCH_ + c;
    part[(pb * D_ + d0 + dl) * N_ + nl] = (st01.x + st01.y) + (st23.x + st23.y);
    if (nl == 0)
        csum[pb * D_ + d0 + dl] = As / A2;
}

// ---------------------------------------------------------------------------
// Kernel 3a: ys[s][b][d] — parallel chunk-combine.
// Grid (S_, B_, D_/16) = 512 blocks; thread = (d-in-tile, n). Each thread
// walks the 16 chunks for its (d,n); n-reduction in LDS.
// ---------------------------------------------------------------------------
__global__ __launch_bounds__(256) void k_ys(const float* __restrict__ x,
                                            const float* __restrict__ Win,
                                            const float* __restrict__ bin,
                                            const float* __restrict__ part,
                                            const float* __restrict__ csum,
                                            const float* __restrict__ A_log,
                                            const float* __restrict__ WC,
                                            const float* __restrict__ Dp,
                                            float* __restrict__ ys)
{
    const int s   = blockIdx.x;
    const int b   = blockIdx.y;
    const int d0  = blockIdx.z * 16;
    const int tid = threadIdx.x;
    const int dl  = tid & 15;
    const int nl  = tid >> 4;
    const int d   = d0 + dl;

    __shared__ float xr[F_];
    __shared__ float hl[D_];
    __shared__ float cred[N_][17];
    __shared__ float cm[N_];
    __shared__ float csh[NCH_][16];
    __shared__ float red[N_][17];

    if (tid < F_) xr[tid] = x[((size_t)b * L_ + (L_ - 1)) * F_ + tid];
    __syncthreads();

    {   // h_last[d'] for all d' (needed for cm)
        float a = bin[tid];
        for (int f = 0; f < F_; ++f) a += xr[f] * Win[(size_t)f * D_ + tid];
        hl[tid] = a;
    }
    __syncthreads();

    {   // cm partials + csum stage
        const int n  = tid & 15;
        const int dq = tid >> 4;
        float a = 0.f;
        for (int dd = dq * 16; dd < dq * 16 + 16; ++dd)
            a += hl[dd] * WC[((size_t)s * D_ + dd) * N_ + n];
        cred[n][dq] = a;
        const size_t cbase0 = ((size_t)s * B_ + b) * NCH_;
        csh[tid >> 4][tid & 15] = csum[(cbase0 + (tid >> 4)) * D_ + d0 + (tid & 15)];
    }
    __syncthreads();
    if (tid < N_) {
        float a = 0.f;
        #pragma unroll
        for (int q = 0; q < 16; ++q) a += cred[tid][q];
        cm[tid] = a;
    }
    __syncthreads();

    // per-(d,n) chunk combine
    const float A = -__expf(A_log[((size_t)s * D_ + d) * N_ + nl]);
    const size_t cbase = ((size_t)s * B_ + b) * NCH_;
    float acc = 0.f;
    float tail = 0.f;
    #pragma unroll
    for (int c = NCH_ - 1; c >= 0; --c) {
        const float p = part[((cbase + c) * D_ + d) * N_ + nl];
        acc += __expf(A * tail) * p;
        tail += csh[c][dl];
    }
    red[nl][dl] = cm[nl] * acc;
    __syncthreads();

    if (tid < 16) {
        float a = 0.f;
        #pragma unroll
        for (int n = 0; n < N_; ++n) a += red[n][tid];
        const int dd = d0 + tid;
        ys[((size_t)s * B_ + b) * D_ + dd] = a + hl[dd] * Dp[s * D_ + dd];
    }
}

// ---------------------------------------------------------------------------
// Kernel 3b: last[b][e] = (1/S) sum_{s,d} ys[s][b][d] * Wout[s][d][e].
// Grid (B_, 4 e-tiles) = 64 blocks; 4-way split-K over waves.
// ---------------------------------------------------------------------------
__global__ __launch_bounds__(256) void k_last(const float* __restrict__ ys,
                                              const float* __restrict__ Wout,
                                              float* __restrict__ last)
{
    const int b  = blockIdx.x;
    const int e0 = blockIdx.y * 64;
    const int tid = threadIdx.x;
    const int e  = tid & 63;
    const int kq = tid >> 6;

    __shared__ float ysl[S_ * D_];
    __shared__ float red[4][64];

    #pragma unroll
    for (int j = tid; j < S_ * D_; j += 256) {
        const int ss = j >> 8, dd = j & 255;
        ysl[j] = ys[((size_t)ss * B_ + b) * D_ + dd];
    }
    __syncthreads();

    float a = 0.f;
    for (int k = kq * 128; k < kq * 128 + 128; ++k) {
        const int ss = k >> 8, dd = k & 255;
        a += ysl[k] * Wout[((size_t)ss * D_ + dd) * D_ + e0 + e];
    }
    red[kq][e] = a;
    __syncthreads();
    if (kq == 0) {
        const float v = (red[0][e] + red[1][e] + red[2][e] + red[3][e]) * (1.f / S_);
        last[(size_t)b * D_ + e0 + e] = v;
    }
}

// ---------------------------------------------------------------------------
// Kernel 3c: LayerNorm + MLP head. Grid B_ blocks.
// ---------------------------------------------------------------------------
__global__ __launch_bounds__(256) void k_head(const float* __restrict__ last,
                                              const float* __restrict__ ln_g,
                                              const float* __restrict__ ln_b,
                                              const float* __restrict__ W1,
                                              const float* __restrict__ b1,
                                              const float* __restrict__ W2,
                                              const float* __restrict__ b2,
                                              float* __restrict__ out)
{
    const int b   = blockIdx.x;
    const int tid = threadIdx.x;

    __shared__ float zv[D_];
    __shared__ float red1[256];
    __shared__ float red2[256];
    __shared__ float r1[H_];

    const float v = last[(size_t)b * D_ + tid];
    red1[tid] = v;
    red2[tid] = v * v;
    __syncthreads();
    for (int off = 128; off > 0; off >>= 1) {
        if (tid < off) { red1[tid] += red1[tid + off]; red2[tid] += red2[tid + off]; }
        __syncthreads();
    }
    const float mu  = red1[0] * (1.f / D_);
    const float var = red2[0] * (1.f / D_) - mu * mu;
    const float z = (v - mu) * rsqrtf(var + EPS_) * ln_g[tid] + ln_b[tid];
    zv[tid] = z;
    __syncthreads();

    if (tid < H_) {
        float a = b1[tid];
        for (int e = 0; e < D_; ++e) a += zv[e] * W1[(size_t)e * H_ + tid];
        r1[tid] = fmaxf(a, 0.f);
    }
    __syncthreads();
    if (tid == 0) {
        float a = b2[0];
        for (int j = 0; j < H_; ++j) a += r1[j] * W2[j];
        out[b] = a;
    }
}

// ---------------------------------------------------------------------------
extern "C" void kernel_launch(void* const* d_in, const int* in_sizes, int n_in,
                              void* d_out, int out_size, void* d_ws, size_t ws_size,
                              hipStream_t stream)
{
    const float* x     = (const float*)d_in[0];
    const float* Win   = (const float*)d_in[1];
    const float* bin   = (const float*)d_in[2];
    const float* Wd    = (const float*)d_in[3];
    const float* bd    = (const float*)d_in[4];
    const float* WB    = (const float*)d_in[5];
    const float* WC    = (const float*)d_in[6];
    const float* Wtau  = (const float*)d_in[7];
    const float* A_log = (const float*)d_in[8];
    const float* Dp    = (const float*)d_in[9];
    const float* Wout  = (const float*)d_in[10];
    const float* ln_g  = (const float*)d_in[11];
    const float* ln_b  = (const float*)d_in[12];
    const float* W1    = (const float*)d_in[13];
    const float* b1    = (const float*)d_in[14];
    const float* W2    = (const float*)d_in[15];
    const float* b2    = (const float*)d_in[16];
    float* out = (float*)d_out;

    char* ws = (char*)d_ws;
    const size_t MB = 1024 * 1024;
    const size_t KB = 1024;
    unsigned short* x_hi     = (unsigned short*)(ws);                      // 2 MiB
    unsigned short* Weff_hi  = (unsigned short*)(ws + 2 * MB);             // 128 KiB
    unsigned short* WinT_hi  = (unsigned short*)(ws + 2 * MB + 128 * KB);  // 32 KiB
    unsigned short* WBe_hi   = (unsigned short*)(ws + 2 * MB + 160 * KB);  // 4 KiB
    float*          bias_eff = (float*)(ws + 2 * MB + 164 * KB);           // 4 KiB
    float*          bbias    = (float*)(ws + 2 * MB + 168 * KB);           // 128 B
    float*          part     = (float*)(ws + 3 * MB);                      // 8 MiB (S,B,NCH,D,N)
    float*          csum     = (float*)(ws + 11 * MB);                     // 512 KiB
    float*          ysbuf    = (float*)(ws + 11 * MB + 512 * KB);          // 32 KiB
    float*          lastbuf  = (float*)(ws + 11 * MB + 544 * KB);          // 16 KiB

    hipLaunchKernelGGL(k_prep, dim3(XBLK_ + 328), dim3(256), 0, stream,
                       x, Win, bin, Wd, bd, Wtau, WB,
                       x_hi, Weff_hi, bias_eff, WinT_hi, WBe_hi, bbias);
    hipLaunchKernelGGL(k_fused_scan, dim3((D_ / 16) * NCH_, B_, S_), dim3(256), 0, stream,
                       x_hi, Weff_hi, WinT_hi, WBe_hi,
                       bias_eff, bin, bbias, A_log, part, csum);
    hipLaunchKernelGGL(k_ys,   dim3(S_, B_, D_ / 16), dim3(256), 0, stream,
                       x, Win, bin, part, csum, A_log, WC, Dp, ysbuf);
    hipLaunchKernelGGL(k_last, dim3(B_, 4), dim3(256), 0, stream, ysbuf, Wout, lastbuf);
    hipLaunchKernelGGL(k_head, dim3(B_), dim3(256), 0, stream,
                       lastbuf, ln_g, ln_b, W1, b1, W2, b2, out);
}

// Round 15
// 161.119 us; speedup vs baseline: 1.1170x; 1.0031x over previous
//
#include <hip/hip_runtime.h>
#include <hip/hip_bf16.h>
#include <math.h>

#define B_   16
#define L_   1024
#define F_   64
#define D_   256
#define S_   2
#define N_   16
#define H_   32
#define EPS_ 1e-5f
#define BL_  (B_*L_)
#define NCH_ 16         // t-chunks for the parallel scan
#define TC_  (L_/NCH_)  // 64 timesteps per chunk (one sub-chunk)
#define TSTR_ 68        // scan tile stride (floats); 272B rows, 16B aligned
#define LOG2E_ 1.44269504088896340736f
#define XBLK_ (BL_*F_/1024)   // 1024 xsplit blocks

typedef __attribute__((ext_vector_type(8))) short  bf16x8;
typedef __attribute__((ext_vector_type(4))) float  f32x4;
typedef __attribute__((ext_vector_type(2))) float  f32x2;

typedef const __attribute__((address_space(1))) void* gas_ptr;
typedef __attribute__((address_space(3))) void*       las_ptr;

#if defined(__has_builtin)
# if __has_builtin(__builtin_amdgcn_exp2f)
#  define EXP2(x) __builtin_amdgcn_exp2f(x)
#  define ASCALE_ LOG2E_
# endif
#endif
#ifndef EXP2
# define EXP2(x) __expf(x)
# define ASCALE_ 1.0f
#endif

__device__ inline void async_copy16(const void* g, void* l) {
    __builtin_amdgcn_global_load_lds((gas_ptr)g, (las_ptr)l, 16, 0, 0);
}

__device__ inline unsigned short f2bf_rne(float x) {
    union { float f; unsigned u; } v; v.f = x;
    unsigned r = v.u + 0x7fff + ((v.u >> 16) & 1);
    return (unsigned short)(r >> 16);
}

// ---------------------------------------------------------------------------
// Kernel 1: combined prep (x -> bf16, composed weights -> bf16).
// ---------------------------------------------------------------------------
__global__ __launch_bounds__(256) void k_prep(const float* __restrict__ x,
                                              const float* __restrict__ Win,
                                              const float* __restrict__ bin,
                                              const float* __restrict__ Wd,
                                              const float* __restrict__ bd,
                                              const float* __restrict__ Wt,
                                              const float* __restrict__ WB,
                                              unsigned short* __restrict__ x_hi,
                                              unsigned short* __restrict__ Weff_hi,
                                              float* __restrict__ bias_eff,
                                              unsigned short* __restrict__ WinT_hi,
                                              unsigned short* __restrict__ WBe_hi,
                                              float* __restrict__ bbias)
{
    const int blk = blockIdx.x;
    const int tid = threadIdx.x;

    if (blk < XBLK_) {
        const int i = (blk * 256 + tid) * 4;
        float4 v = *(const float4*)(x + i);
        ushort4 h4;
        h4.x = f2bf_rne(v.x);
        h4.y = f2bf_rne(v.y);
        h4.z = f2bf_rne(v.z);
        h4.w = f2bf_rne(v.w);
        *(ushort4*)(x_hi + i) = h4;
        return;
    }

    const int job4 = blk - XBLK_;
    const int j    = tid >> 6;          // sub-job 0..3
    const int f    = tid & 63;
    const int job  = job4 * 4 + j;

    __shared__ float col[4][D_];

    if (job < 1024) {                   // Weff: s = job>>9, n = job&511
        const int s = job >> 9, n = job & 511;
        const float* W = (n < 256) ? (Wd + (size_t)s * D_ * D_) : (Wt + (size_t)s * D_ * D_);
        const int e = n & 255;
        for (int d = f; d < D_; d += 64) col[j][d] = W[(size_t)d * D_ + e];
        __syncthreads();
        float a = 0.f;
        for (int d = 0; d < D_; ++d) a += Win[(size_t)f * D_ + d] * col[j][d];
        Weff_hi[((size_t)s * 512 + n) * F_ + f] = f2bf_rne(a);
        if (f == 0) {
            float bb = 0.f;
            for (int d = 0; d < D_; ++d) bb += bin[d] * col[j][d];
            if (n < 256) bb += bd[s * D_ + e];
            bias_eff[s * 512 + n] = bb;
        }
    } else if (job < 1024 + D_) {       // WinT
        const int d = job - 1024;
        WinT_hi[(size_t)d * F_ + f] = f2bf_rne(Win[(size_t)f * D_ + d]);
    } else {                            // WBe
        const int idx = job - (1024 + D_);
        const int s = idx >> 4, n = idx & 15;
        const float* wb = WB + (size_t)s * D_ * N_;
        float a = 0.f;
        for (int d = 0; d < D_; ++d) a += Win[(size_t)f * D_ + d] * wb[(size_t)d * N_ + n];
        WBe_hi[((size_t)s * N_ + n) * F_ + f] = f2bf_rne(a);
        if (f == 0) {
            float bb = 0.f;
            for (int d = 0; d < D_; ++d) bb += bin[d] * wb[(size_t)d * N_ + n];
            bbias[s * N_ + n] = bb;
        }
    }
}

// ---------------------------------------------------------------------------
// Kernel 2: FUSED gemm + activation + scan, bf16 GEMM, single 64-t chunk
// per block (NCH=16), 2 barriers. Scan: 2 independent 32-t segments per
// thread (2x ILP on the serial As/exp chain), combined at the end.
// ---------------------------------------------------------------------------
__global__ __launch_bounds__(256) void k_fused_scan(
        const unsigned short* __restrict__ x_hi,
        const unsigned short* __restrict__ Weff_hi,
        const unsigned short* __restrict__ WinT_hi,
        const unsigned short* __restrict__ WBe_hi,
        const float* __restrict__ bias_eff,
        const float* __restrict__ bin,
        const float* __restrict__ bbias,
        const float* __restrict__ A_log,
        float* __restrict__ part,
        float* __restrict__ csum)
{
    const int dtile = blockIdx.x >> 4;
    const int c     = blockIdx.x & 15;
    const int b     = blockIdx.y;
    const int s     = blockIdx.z;
    const int d0    = dtile * 16;
    const int tid   = threadIdx.x;
    const int wid   = tid >> 6;
    const int lane  = tid & 63;
    const int l15   = lane & 15;
    const int quad  = lane >> 4;
    const int dl    = tid & 15;
    const int nl    = tid >> 4;

    __shared__ unsigned short Wh[64 * F_];  // [col][f]: 0-15 d,16-31 tau,32-47 Win,48-63 WB
    __shared__ float sdl[16][TSTR_];        // [d][t] delta
    __shared__ float sq [16][TSTR_];        // [d][t] delta*h
    __shared__ float sb [16][TSTR_];        // [n][t] Bm

    const int r8 = lane >> 3;
    const int c8 = lane & 7;

    // ---- stage W strip (wave wid = col group wid)
    #pragma unroll
    for (int call = 0; call < 2; ++call) {
        const int rr = call * 8 + r8;
        const int ar = wid * 16 + rr;
        const int lc = (c8 - ar) & 7;
        const unsigned short* gh;
        if (wid == 0)      gh = Weff_hi + ((size_t)s * 512 + d0 + rr) * F_ + lc * 8;
        else if (wid == 1) gh = Weff_hi + ((size_t)s * 512 + 256 + d0 + rr) * F_ + lc * 8;
        else if (wid == 2) gh = WinT_hi + ((size_t)(d0 + rr)) * F_ + lc * 8;
        else               gh = WBe_hi + ((size_t)s * N_ + rr) * F_ + lc * 8;
        async_copy16(gh, &Wh[(wid * 16 + call * 8) * F_]);
    }

    const float bias_d = bias_eff[s * 512 + d0 + l15];
    const float bias_t = bias_eff[s * 512 + 256 + d0 + l15];
    const float bin_v  = bin[d0 + l15];
    const float bb_v   = bbias[s * N_ + l15];
    const float A2 = -__expf(A_log[((size_t)s * D_ + d0 + dl) * N_ + nl]) * ASCALE_;

    // A-fragments for this block's 64-t chunk
    const int qoff = quad * 8;
    bf16x8 fah0, fah1;
    {
        const size_t rowb = ((size_t)b * L_ + c * TC_ + wid * 16 + l15) * F_;
        fah0 = *(const bf16x8*)(x_hi + rowb + qoff);
        fah1 = *(const bf16x8*)(x_hi + rowb + 32 + qoff);
    }
    __syncthreads();   // W staged

    // ---- MFMA: this wave's 16 t-rows x 4 col groups, K=64
    f32x4 acc[4];
    #pragma unroll
    for (int g = 0; g < 4; ++g) acc[g] = (f32x4){0.f, 0.f, 0.f, 0.f};
    #pragma unroll
    for (int ks = 0; ks < 2; ++ks) {
        bf16x8 ah = ks ? fah1 : fah0;
        #pragma unroll
        for (int g = 0; g < 4; ++g) {
            const int brow = g * 16 + l15;
            const int pcB  = ((ks * 4 + quad) + brow) & 7;
            bf16x8 bh = *(const bf16x8*)&Wh[brow * F_ + pcB * 8];
            acc[g] = __builtin_amdgcn_mfma_f32_16x16x32_bf16(ah, bh, acc[g], 0, 0, 0);
        }
    }

    // ---- epilogue: C layout col=l15, row=quad*4+r -> transposed tiles
    {
        f32x4 wd_, wq_, wb_;
        #pragma unroll
        for (int r = 0; r < 4; ++r) {
            const float pd  = acc[0][r] + bias_d;
            const float sp  = fmaxf(pd, 0.f) + __logf(1.f + __expf(-fabsf(pd)));
            const float sg  = 1.f / (1.f + __expf(-(acc[1][r] + bias_t)));
            const float dlt = sp * sg;
            const float hv  = acc[2][r] + bin_v;
            wd_[r] = dlt;
            wq_[r] = dlt * hv;
            wb_[r] = acc[3][r] + bb_v;
        }
        const int tcol = wid * 16 + quad * 4;
        *(f32x4*)&sdl[l15][tcol] = wd_;
        *(f32x4*)&sq [l15][tcol] = wq_;
        *(f32x4*)&sb [l15][tcol] = wb_;
    }
    __syncthreads();

    // ---- backward suffix scan: 2 independent 32-t segments (2x ILP)
    f32x2 stA0 = {0.f, 0.f}, stA1 = {0.f, 0.f};
    f32x2 stB0 = {0.f, 0.f}, stB1 = {0.f, 0.f};
    float As0 = 0.f, As1 = 0.f;
    #pragma unroll
    for (int it = 7; it >= 0; --it) {
        {   // segment 0: t in [0,32)
            const int tt = it * 4;
            f32x4 dp = *(const f32x4*)&sdl[dl][tt];
            f32x4 qp = *(const f32x4*)&sq [dl][tt];
            f32x4 bp = *(const f32x4*)&sb [nl][tt];
            const float a2v = fmaf(A2, dp.w, As0);
            const float a1v = fmaf(A2, dp.z, a2v);
            const float a0v = fmaf(A2, dp.y, a1v);
            f32x2 e01, e23;
            e23.y = EXP2(As0);
            e23.x = EXP2(a2v);
            e01.y = EXP2(a1v);
            e01.x = EXP2(a0v);
            f32x2 q01 = {qp.x, qp.y}, q23 = {qp.z, qp.w};
            f32x2 b01 = {bp.x, bp.y}, b23 = {bp.z, bp.w};
            stA0 = q01 * b01 * e01 + stA0;
            stA1 = q23 * b23 * e23 + stA1;
            As0 = fmaf(A2, dp.x, a0v);
        }
        {   // segment 1: t in [32,64)
            const int tt = 32 + it * 4;
            f32x4 dp = *(const f32x4*)&sdl[dl][tt];
            f32x4 qp = *(const f32x4*)&sq [dl][tt];
            f32x4 bp = *(const f32x4*)&sb [nl][tt];
            const float a2v = fmaf(A2, dp.w, As1);
            const float a1v = fmaf(A2, dp.z, a2v);
            const float a0v = fmaf(A2, dp.y, a1v);
            f32x2 e01, e23;
            e23.y = EXP2(As1);
            e23.x = EXP2(a2v);
            e01.y = EXP2(a1v);
            e01.x = EXP2(a0v);
            f32x2 q01 = {qp.x, qp.y}, q23 = {qp.z, qp.w};
            f32x2 b01 = {bp.x, bp.y}, b23 = {bp.z, bp.w};
            stB0 = q01 * b01 * e01 + stB0;
            stB1 = q23 * b23 * e23 + stB1;
            As1 = fmaf(A2, dp.x, a0v);
        }
    }
    // combine: segment 1 is later in time (no decay); segment 0 decays by As1
    const float seg0 = stA0.x + stA0.y + stA1.x + stA1.y;
    const float seg1 = stB0.x + stB0.y + stB1.x + stB1.y;
    const float state = seg1 + EXP2(As1) * seg0;
    const float Atot  = As1 + As0;

    const size_t pb = ((size_t)s * B_ + b) * NCH_ + c;
    part[(pb * D_ + d0 + dl) * N_ + nl] = state;
    if (nl == 0)
        csum[pb * D_ + d0 + dl] = Atot / A2;
}

// ---------------------------------------------------------------------------
// Kernel 3a: ys[s][b][d] — parallel chunk-combine.
// Grid (S_, B_, D_/16) = 512 blocks; thread = (d-in-tile, n).
// ---------------------------------------------------------------------------
__global__ __launch_bounds__(256) void k_ys(const float* __restrict__ x,
                                            const float* __restrict__ Win,
                                            const float* __restrict__ bin,
                                            const float* __restrict__ part,
                                            const float* __restrict__ csum,
                                            const float* __restrict__ A_log,
                                            const float* __restrict__ WC,
                                            const float* __restrict__ Dp,
                                            float* __restrict__ ys)
{
    const int s   = blockIdx.x;
    const int b   = blockIdx.y;
    const int d0  = blockIdx.z * 16;
    const int tid = threadIdx.x;
    const int dl  = tid & 15;
    const int nl  = tid >> 4;
    const int d   = d0 + dl;

    __shared__ float xr[F_];
    __shared__ float hl[D_];
    __shared__ float cred[N_][17];
    __shared__ float cm[N_];
    __shared__ float csh[NCH_][16];
    __shared__ float red[N_][17];

    if (tid < F_) xr[tid] = x[((size_t)b * L_ + (L_ - 1)) * F_ + tid];
    __syncthreads();

    {   // h_last[d'] for all d' (needed for cm)
        float a = bin[tid];
        for (int f = 0; f < F_; ++f) a += xr[f] * Win[(size_t)f * D_ + tid];
        hl[tid] = a;
    }
    __syncthreads();

    {   // cm partials + csum stage
        const int n  = tid & 15;
        const int dq = tid >> 4;
        float a = 0.f;
        for (int dd = dq * 16; dd < dq * 16 + 16; ++dd)
            a += hl[dd] * WC[((size_t)s * D_ + dd) * N_ + n];
        cred[n][dq] = a;
        const size_t cbase0 = ((size_t)s * B_ + b) * NCH_;
        csh[tid >> 4][tid & 15] = csum[(cbase0 + (tid >> 4)) * D_ + d0 + (tid & 15)];
    }
    __syncthreads();
    if (tid < N_) {
        float a = 0.f;
        #pragma unroll
        for (int q = 0; q < 16; ++q) a += cred[tid][q];
        cm[tid] = a;
    }
    __syncthreads();

    // per-(d,n) chunk combine
    const float A = -__expf(A_log[((size_t)s * D_ + d) * N_ + nl]);
    const size_t cbase = ((size_t)s * B_ + b) * NCH_;
    float acc = 0.f;
    float tail = 0.f;
    #pragma unroll
    for (int c = NCH_ - 1; c >= 0; --c) {
        const float p = part[((cbase + c) * D_ + d) * N_ + nl];
        acc += __expf(A * tail) * p;
        tail += csh[c][dl];
    }
    red[nl][dl] = cm[nl] * acc;
    __syncthreads();

    if (tid < 16) {
        float a = 0.f;
        #pragma unroll
        for (int n = 0; n < N_; ++n) a += red[n][tid];
        const int dd = d0 + tid;
        ys[((size_t)s * B_ + b) * D_ + dd] = a + hl[dd] * Dp[s * D_ + dd];
    }
}

// ---------------------------------------------------------------------------
// Kernel 3b: last[b][e] = (1/S) sum_{s,d} ys[s][b][d] * Wout[s][d][e].
// ---------------------------------------------------------------------------
__global__ __launch_bounds__(256) void k_last(const float* __restrict__ ys,
                                              const float* __restrict__ Wout,
                                              float* __restrict__ last)
{
    const int b  = blockIdx.x;
    const int e0 = blockIdx.y * 64;
    const int tid = threadIdx.x;
    const int e  = tid & 63;
    const int kq = tid >> 6;

    __shared__ float ysl[S_ * D_];
    __shared__ float red[4][64];

    #pragma unroll
    for (int j = tid; j < S_ * D_; j += 256) {
        const int ss = j >> 8, dd = j & 255;
        ysl[j] = ys[((size_t)ss * B_ + b) * D_ + dd];
    }
    __syncthreads();

    float a = 0.f;
    for (int k = kq * 128; k < kq * 128 + 128; ++k) {
        const int ss = k >> 8, dd = k & 255;
        a += ysl[k] * Wout[((size_t)ss * D_ + dd) * D_ + e0 + e];
    }
    red[kq][e] = a;
    __syncthreads();
    if (kq == 0) {
        const float v = (red[0][e] + red[1][e] + red[2][e] + red[3][e]) * (1.f / S_);
        last[(size_t)b * D_ + e0 + e] = v;
    }
}

// ---------------------------------------------------------------------------
// Kernel 3c: LayerNorm + MLP head. Grid B_ blocks.
// ---------------------------------------------------------------------------
__global__ __launch_bounds__(256) void k_head(const float* __restrict__ last,
                                              const float* __restrict__ ln_g,
                                              const float* __restrict__ ln_b,
                                              const float* __restrict__ W1,
                                              const float* __restrict__ b1,
                                              const float* __restrict__ W2,
                                              const float* __restrict__ b2,
                                              float* __restrict__ out)
{
    const int b   = blockIdx.x;
    const int tid = threadIdx.x;

    __shared__ float zv[D_];
    __shared__ float red1[256];
    __shared__ float red2[256];
    __shared__ float r1[H_];

    const float v = last[(size_t)b * D_ + tid];
    red1[tid] = v;
    red2[tid] = v * v;
    __syncthreads();
    for (int off = 128; off > 0; off >>= 1) {
        if (tid < off) { red1[tid] += red1[tid + off]; red2[tid] += red2[tid + off]; }
        __syncthreads();
    }
    const float mu  = red1[0] * (1.f / D_);
    const float var = red2[0] * (1.f / D_) - mu * mu;
    const float z = (v - mu) * rsqrtf(var + EPS_) * ln_g[tid] + ln_b[tid];
    zv[tid] = z;
    __syncthreads();

    if (tid < H_) {
        float a = b1[tid];
        for (int e = 0; e < D_; ++e) a += zv[e] * W1[(size_t)e * H_ + tid];
        r1[tid] = fmaxf(a, 0.f);
    }
    __syncthreads();
    if (tid == 0) {
        float a = b2[0];
        for (int j = 0; j < H_; ++j) a += r1[j] * W2[j];
        out[b] = a;
    }
}

// ---------------------------------------------------------------------------
extern "C" void kernel_launch(void* const* d_in, const int* in_sizes, int n_in,
                              void* d_out, int out_size, void* d_ws, size_t ws_size,
                              hipStream_t stream)
{
    const float* x     = (const float*)d_in[0];
    const float* Win   = (const float*)d_in[1];
    const float* bin   = (const float*)d_in[2];
    const float* Wd    = (const float*)d_in[3];
    const float* bd    = (const float*)d_in[4];
    const float* WB    = (const float*)d_in[5];
    const float* WC    = (const float*)d_in[6];
    const float* Wtau  = (const float*)d_in[7];
    const float* A_log = (const float*)d_in[8];
    const float* Dp    = (const float*)d_in[9];
    const float* Wout  = (const float*)d_in[10];
    const float* ln_g  = (const float*)d_in[11];
    const float* ln_b  = (const float*)d_in[12];
    const float* W1    = (const float*)d_in[13];
    const float* b1    = (const float*)d_in[14];
    const float* W2    = (const float*)d_in[15];
    const float* b2    = (const float*)d_in[16];
    float* out = (float*)d_out;

    char* ws = (char*)d_ws;
    const size_t MB = 1024 * 1024;
    const size_t KB = 1024;
    unsigned short* x_hi     = (unsigned short*)(ws);                      // 2 MiB
    unsigned short* Weff_hi  = (unsigned short*)(ws + 2 * MB);             // 128 KiB
    unsigned short* WinT_hi  = (unsigned short*)(ws + 2 * MB + 128 * KB);  // 32 KiB
    unsigned short* WBe_hi   = (unsigned short*)(ws + 2 * MB + 160 * KB);  // 4 KiB
    float*          bias_eff = (float*)(ws + 2 * MB + 164 * KB);           // 4 KiB
    float*          bbias    = (float*)(ws + 2 * MB + 168 * KB);           // 128 B
    float*          part     = (float*)(ws + 3 * MB);                      // 8 MiB (S,B,NCH,D,N)
    float*          csum     = (float*)(ws + 11 * MB);                     // 512 KiB
    float*          ysbuf    = (float*)(ws + 11 * MB + 512 * KB);          // 32 KiB
    float*          lastbuf  = (float*)(ws + 11 * MB + 544 * KB);          // 16 KiB

    hipLaunchKernelGGL(k_prep, dim3(XBLK_ + 328), dim3(256), 0, stream,
                       x, Win, bin, Wd, bd, Wtau, WB,
                       x_hi, Weff_hi, bias_eff, WinT_hi, WBe_hi, bbias);
    hipLaunchKernelGGL(k_fused_scan, dim3((D_ / 16) * NCH_, B_, S_), dim3(256), 0, stream,
                       x_hi, Weff_hi, WinT_hi, WBe_hi,
                       bias_eff, bin, bbias, A_log, part, csum);
    hipLaunchKernelGGL(k_ys,   dim3(S_, B_, D_ / 16), dim3(256), 0, stream,
                       x, Win, bin, part, csum, A_log, WC, Dp, ysbuf);
    hipLaunchKernelGGL(k_last, dim3(B_, 4), dim3(256), 0, stream, ysbuf, Wout, lastbuf);
    hipLaunchKernelGGL(k_head, dim3(B_), dim3(256), 0, stream,
                       lastbuf, ln_g, ln_b, W1, b1, W2, b2, out);
}